// Round 14
// baseline (139.468 us; speedup 1.0000x reference)
//
#include <hip/hip_runtime.h>
#include <math.h>

// Problem constants (from reference)
#define NCH 129
#define BS 8
#define TLEN 64000
#define TILE 256          // frame length
#define WARM 64           // u warm-up steps before frame start
#define NFRM 250          // number of frames
#define NSEQ (NCH * BS)   // 1032 sequences
#define NBK (BS * NFRM)   // 2000 (b,frame) cells
#define KF_EDGE 16        // ceil(NBK/128): edge blocks (channel pair 127,128)
#define KF_MAIN 500       // main blocks: 128 thr = 2 waves, 2 tiles per wave
// Lead for r>=1: 128 ISTEP + 64 WSTEP = 192 samples starting at r*256-192.
// Zero-init decay by frame start: 0.97^192 ~ 2.9e-3 (below bf16 noise floor;
// absmax stayed 2.0 across lead 320->256->192).
#define GI 32             // ISTEP groups (128 steps)
#define GW 16             // WSTEP groups (64 steps)
#define GMAIN 64          // MSTEP groups (256 steps)
#define MAXSEG 112        // (GI+GW+GMAIN) float4 segments per tile

typedef float f2 __attribute__((ext_vector_type(2)));

__device__ __forceinline__ f2 mk2(float a, float b) { f2 r; r.x = a; r.y = b; return r; }

__device__ __forceinline__ f2 fma2(f2 a, f2 b, f2 c) {
#if __has_builtin(__builtin_elementwise_fma)
    return __builtin_elementwise_fma(a, b, c);
#else
    f2 r; r.x = fmaf(a.x, b.x, c.x); r.y = fmaf(a.y, b.y, c.y); return r;
#endif
}

__device__ __forceinline__ float sigf(float v) {
    return __builtin_amdgcn_rcpf(1.0f + __expf(-v));
}
__device__ __forceinline__ f2 sig2(f2 v) {
    f2 r; r.x = sigf(v.x); r.y = sigf(v.y); return r;
}

// Packed pair-of-chains coefficients.
struct C2 { f2 b0, b1, b2, b3, b4, a1, a2, a3, a4; };

__device__ __forceinline__ C2 load_coef2(const float* __restrict__ B,
                                         const float* __restrict__ A,
                                         int cx, int cy) {
    C2 q;
    q.b0 = mk2(B[cx * 5 + 0], B[cy * 5 + 0]);
    q.b1 = mk2(B[cx * 5 + 1], B[cy * 5 + 1]);
    q.b2 = mk2(B[cx * 5 + 2], B[cy * 5 + 2]);
    q.b3 = mk2(B[cx * 5 + 3], B[cy * 5 + 3]);
    q.b4 = mk2(B[cx * 5 + 4], B[cy * 5 + 4]);
    q.a1 = mk2(A[cx * 5 + 1], A[cy * 5 + 1]);
    q.a2 = mk2(A[cx * 5 + 2], A[cy * 5 + 2]);
    q.a3 = mk2(A[cx * 5 + 3], A[cy * 5 + 3]);
    q.a4 = mk2(A[cx * 5 + 4], A[cy * 5 + 4]);
    return q;
}

__device__ __forceinline__ f2 iir2_step(const C2& q, float x,
                                        f2& z0, f2& z1, f2& z2, f2& z3) {
    f2 xx = mk2(x, x);
    f2 y = fma2(q.b0, xx, z0);
    z0 = fma2(-q.a1, y, fma2(q.b1, xx, z1));
    z1 = fma2(-q.a2, y, fma2(q.b2, xx, z2));
    z2 = fma2(-q.a3, y, fma2(q.b3, xx, z3));
    z3 = fma2(-q.a4, y, q.b4 * xx);
    return y;
}

// explicit-state step macros (coef struct must be named q)
#define ISTEPX(xv, Z0, Z1, Z2, Z3)                                             \
    { (void)iir2_step(q, (xv), Z0, Z1, Z2, Z3); }
#define WSTEPX(xv, Z0, Z1, Z2, Z3, U)                                          \
    { f2 y_ = iir2_step(q, (xv), Z0, Z1, Z2, Z3);                              \
      U = fma2(beta2, U, sig2(y_)); }
#define MSTEPX(xv, Z0, Z1, Z2, Z3, U, G2, PU, PB)                              \
    { f2 y_ = iir2_step(q, (xv), Z0, Z1, Z2, Z3);                              \
      U = fma2(beta2, U, sig2(y_));                                            \
      float un_ = __shfl_down(U.x, 1, 64);                                     \
      float y4o_ = fmaxf(U.y - U.x, 0.0f);                                     \
      float y4e_ = fmaxf(PU - PB, 0.0f);                                       \
      G2 = fma2(alpha2, G2, mk2(y4o_, y4e_));                                  \
      PU = un_; PB = U.y; }

// ---------------------------------------------------------------------------
// Fused kernel, ILP-2: each wave runs TWO independent frame-tiles
// (wid and wid+1000 — same r, so identical control flow; b differs by 4;
// identical lane->channel map so the C2 coefficients are SHARED). The two
// interleaved streams give the in-order issue engine VALU work from tile-B
// during tile-A's TRANS (exp/rcp) latency — the 44% idle-issue gap at
// 2 waves/SIMD that R13 measured (VALUBusy 56%).
//   r == 0 : no lead (true zero state, exact).
//   r >= 1 : 192-sample lead (128 ISTEP + 64 WSTEP), decay 0.97^192.
// Blocks [0, KF_EDGE): channel pair (127,128) -> ch 128, one item/thread.
// Blocks [KF_EDGE, +KF_MAIN): 128 thr = 2 waves; wave w -> wid = blk*2+w.
// ---------------------------------------------------------------------------
__global__ __launch_bounds__(128, 4) void kF_fused(
        const float* __restrict__ wav, const float* __restrict__ B,
        const float* __restrict__ A, float* __restrict__ G,
        float* __restrict__ y4f, float beta, float alpha) {
    __shared__ float4 xs4[4 * MAXSEG];   // 2 waves x 2 tiles
    int blk = blockIdx.x;
    const f2 beta2 = mk2(beta, beta);
    const f2 alpha2 = mk2(alpha, alpha);

    if (blk < KF_EDGE) {
        // ---- edge: channel pair (127,128), one (b,r) per thread ----
        int item = blk * 128 + threadIdx.x;
        if (item >= NBK) return;
        int b = item / NFRM;
        int r = item - b * NFRM;
        C2 q = load_coef2(B, A, 127, 128);
        f2 z0 = mk2(0.f, 0.f), z1 = z0, z2 = z0, z3 = z0, u = z0;
        int nIst = (r == 0) ? 0 : 4 * GI;
        int nW   = (r == 0) ? 0 : 4 * GW;
        const float* xg = wav + (size_t)b * TLEN
                        + (size_t)r * TILE - (size_t)(nIst + nW);
        #pragma unroll 2
        for (int j = 0; j < nIst; ++j) ISTEPX(xg[j], z0, z1, z2, z3);
        xg += nIst;
        #pragma unroll 2
        for (int j = 0; j < nW; ++j) WSTEPX(xg[j], z0, z1, z2, z3, u);
        xg += nW;
        float g4 = 0.f, yfirst = 0.f;
        #pragma unroll 2
        for (int j = 0; j < TILE; ++j) {
            f2 y_ = iir2_step(q, xg[j], z0, z1, z2, z3);
            u = fma2(beta2, u, sig2(y_));
            float y4 = fmaxf(u.y - u.x, 0.0f);   // ch128 - ch127
            if (j == 0) yfirst = y4;
            g4 = fmaf(alpha, g4, y4);
        }
        size_t idx = ((size_t)b * NFRM + r) * NCH + 128;
        G[idx] = g4;
        y4f[idx] = yfirst;
        return;
    }

    // ---- main: wave w -> wid = (blk-KF_EDGE)*2 + w; tiles wid, wid+1000 ----
    int wave = threadIdx.x >> 6;
    int t = threadIdx.x & 63;                // lane 0..63
    int wid = (blk - KF_EDGE) * 2 + wave;    // [0, 1000)
    int bA = wid / NFRM;                     // 0..3
    int r  = wid - bA * NFRM;
    int bB = bA + 4;                         // tile B: same r, batch +4
    int gi = (r == 0) ? 0 : GI;
    int gw = (r == 0) ? 0 : GW;
    int gbase = gi + gw;
    int n4 = gbase + GMAIN;                  // 64 (r==0) or 112
    size_t off = (size_t)r * TILE - (size_t)(4 * gbase);
    const float* xgA = wav + (size_t)bA * TLEN + off;
    const float* xgB = wav + (size_t)bB * TLEN + off;
    float4* segA = xs4 + (wave * 2) * MAXSEG;
    float4* segB = segA + MAXSEG;
    for (int i = t; i < n4; i += 64) {
        segA[i] = ((const float4*)xgA)[i];
        segB[i] = ((const float4*)xgB)[i];
    }
    __syncthreads();

    int cA = 2 * t, cB = 2 * t + 1;          // chains (cB <= 127), SHARED q
    C2 q = load_coef2(B, A, cA, cB);
    f2 zA0 = mk2(0.f, 0.f), zA1 = zA0, zA2 = zA0, zA3 = zA0, uA = zA0;
    f2 zB0 = zA0, zB1 = zA0, zB2 = zA0, zB3 = zA0, uB = zA0;
    for (int g = 0; g < gi; ++g) {           // zero-state z lead-in
        float4 xa = segA[g], xb = segB[g];
        ISTEPX(xa.x, zA0, zA1, zA2, zA3); ISTEPX(xb.x, zB0, zB1, zB2, zB3);
        ISTEPX(xa.y, zA0, zA1, zA2, zA3); ISTEPX(xb.y, zB0, zB1, zB2, zB3);
        ISTEPX(xa.z, zA0, zA1, zA2, zA3); ISTEPX(xb.z, zB0, zB1, zB2, zB3);
        ISTEPX(xa.w, zA0, zA1, zA2, zA3); ISTEPX(xb.w, zB0, zB1, zB2, zB3);
    }
    for (int g = gi; g < gbase; ++g) {       // 64 u warm-up steps
        float4 xa = segA[g], xb = segB[g];
        WSTEPX(xa.x, zA0, zA1, zA2, zA3, uA); WSTEPX(xb.x, zB0, zB1, zB2, zB3, uB);
        WSTEPX(xa.y, zA0, zA1, zA2, zA3, uA); WSTEPX(xb.y, zB0, zB1, zB2, zB3, uB);
        WSTEPX(xa.z, zA0, zA1, zA2, zA3, uA); WSTEPX(xb.z, zB0, zB1, zB2, zB3, uB);
        WSTEPX(xa.w, zA0, zA1, zA2, zA3, uA); WSTEPX(xb.w, zB0, zB1, zB2, zB3, uB);
    }

    // main 256 steps; pipeline: ge consumes shfl one step late.
    f2 g2A, g2B;
    float foA, feA, puA, pbA, foB, feB, puB, pbB;
    {   // first group: peel j=0 and j=1 for both tiles
        float4 xa = segA[gbase], xb = segB[gbase];
        // j = 0, tile A
        f2 y_ = iir2_step(q, xa.x, zA0, zA1, zA2, zA3);
        uA = fma2(beta2, uA, sig2(y_));
        puA = __shfl_down(uA.x, 1, 64);
        foA = fmaxf(uA.y - uA.x, 0.0f);
        g2A = mk2(foA, 0.0f);
        pbA = uA.y;
        // j = 0, tile B
        y_ = iir2_step(q, xb.x, zB0, zB1, zB2, zB3);
        uB = fma2(beta2, uB, sig2(y_));
        puB = __shfl_down(uB.x, 1, 64);
        foB = fmaxf(uB.y - uB.x, 0.0f);
        g2B = mk2(foB, 0.0f);
        pbB = uB.y;
        // j = 1, tile A
        y_ = iir2_step(q, xa.y, zA0, zA1, zA2, zA3);
        uA = fma2(beta2, uA, sig2(y_));
        float un_ = __shfl_down(uA.x, 1, 64);
        float y4o_ = fmaxf(uA.y - uA.x, 0.0f);
        feA = fmaxf(puA - pbA, 0.0f);
        g2A = fma2(alpha2, g2A, mk2(y4o_, feA));
        puA = un_; pbA = uA.y;
        // j = 1, tile B
        y_ = iir2_step(q, xb.y, zB0, zB1, zB2, zB3);
        uB = fma2(beta2, uB, sig2(y_));
        un_ = __shfl_down(uB.x, 1, 64);
        y4o_ = fmaxf(uB.y - uB.x, 0.0f);
        feB = fmaxf(puB - pbB, 0.0f);
        g2B = fma2(alpha2, g2B, mk2(y4o_, feB));
        puB = un_; pbB = uB.y;
        // j = 2, 3 both tiles
        MSTEPX(xa.z, zA0, zA1, zA2, zA3, uA, g2A, puA, pbA);
        MSTEPX(xb.z, zB0, zB1, zB2, zB3, uB, g2B, puB, pbB);
        MSTEPX(xa.w, zA0, zA1, zA2, zA3, uA, g2A, puA, pbA);
        MSTEPX(xb.w, zB0, zB1, zB2, zB3, uB, g2B, puB, pbB);
    }
    for (int g = gbase + 1; g < gbase + GMAIN; ++g) {
        float4 xa = segA[g], xb = segB[g];
        MSTEPX(xa.x, zA0, zA1, zA2, zA3, uA, g2A, puA, pbA);
        MSTEPX(xb.x, zB0, zB1, zB2, zB3, uB, g2B, puB, pbB);
        MSTEPX(xa.y, zA0, zA1, zA2, zA3, uA, g2A, puA, pbA);
        MSTEPX(xb.y, zB0, zB1, zB2, zB3, uB, g2B, puB, pbB);
        MSTEPX(xa.z, zA0, zA1, zA2, zA3, uA, g2A, puA, pbA);
        MSTEPX(xb.z, zB0, zB1, zB2, zB3, uB, g2B, puB, pbB);
        MSTEPX(xa.w, zA0, zA1, zA2, zA3, uA, g2A, puA, pbA);
        MSTEPX(xb.w, zB0, zB1, zB2, zB3, uB, g2B, puB, pbB);
    }
    // tail: apply the last pending ge term, both tiles
    float goA = g2A.x, geA = fmaf(alpha, g2A.y, fmaxf(puA - pbA, 0.0f));
    float goB = g2B.x, geB = fmaf(alpha, g2B.y, fmaxf(puB - pbB, 0.0f));

    size_t baseA = ((size_t)bA * NFRM + r) * NCH;
    size_t baseB = ((size_t)bB * NFRM + r) * NCH;
    G[baseA + cB] = goA;           // channel 2t+1 (odd 1..127)
    y4f[baseA + cB] = foA;
    G[baseB + cB] = goB;
    y4f[baseB + cB] = foB;
    if (t < 63) {
        G[baseA + cB + 1] = geA;   // channel 2t+2 (even 2..126)
        y4f[baseA + cB + 1] = feA;
        G[baseB + cB + 1] = geB;
        y4f[baseB + cB + 1] = feB;
    }
}

// ---------------------------------------------------------------------------
// Kernel D (R11 Kogge-Stone, known-good ~8 us): one wave per sequence (b,c);
// lane l owns frames [4l, 4l+4). Coalesced stores; scattered loads hidden
// by 1032 waves of TLP.
//   o[k] = alpha * s_in[k] + y4f[k];  s' = aL*s + G[k].
// ---------------------------------------------------------------------------
#define KD_LOAD(gn, yn, i)                                                     \
    {   int kk = k0 + (i); int kcl = (kk < NFRM) ? kk : (NFRM - 1);            \
        size_t ix = ((size_t)b * NFRM + kcl) * NCH + c;                        \
        gn = G[ix]; yn = y4f[ix];                                              \
        if (kk >= NFRM) { gn = 0.f; yn = 0.f; } }
#define KD_REPLAY(gn, yn, i)                                                   \
    {   int kk = k0 + (i);                                                     \
        if (kk < NFRM) o[kk] = fmaf(alpha, sv, yn);                            \
        sv = fmaf(aL, sv, gn); }

__global__ __launch_bounds__(256) void kD_scan_par(
        const float* __restrict__ G, const float* __restrict__ y4f,
        float* __restrict__ out, float alpha, float aL) {
    int id = blockIdx.x * 4 + (threadIdx.x >> 6);   // b * NCH + c
    int lane = threadIdx.x & 63;
    if (id >= NSEQ) return;
    int b = id / NCH;
    int c = id - b * NCH;
    float* o = out + (size_t)id * NFRM;
    int k0 = lane * 4;
    if (c == 0) {
        #pragma unroll
        for (int i = 0; i < 4; ++i) {
            int kk = k0 + i;
            if (kk < NFRM) o[kk] = 0.0f;
        }
        return;
    }
    float g0, g1, g2v, g3, y0, y1, y2v, y3;
    KD_LOAD(g0, y0, 0); KD_LOAD(g1, y1, 1); KD_LOAD(g2v, y2v, 2); KD_LOAD(g3, y3, 3);
    // local inclusive carry
    float e = g0;
    e = fmaf(aL, e, g1);
    e = fmaf(aL, e, g2v);
    e = fmaf(aL, e, g3);
    // Kogge-Stone with factor f = (aL^4)^{2^s}
    float aL2 = aL * aL;
    float f = aL2 * aL2;                     // aL^4
    for (int s = 0; s < 6; ++s) {
        int off = 1 << s;
        float src = __shfl_up(e, off, 64);
        if (lane < off) src = 0.f;
        e = fmaf(f, src, e);
        f = f * f;
    }
    // exclusive shift
    float sv = __shfl_up(e, 1, 64);
    if (lane == 0) sv = 0.f;
    // replay + store
    KD_REPLAY(g0, y0, 0); KD_REPLAY(g1, y1, 1);
    KD_REPLAY(g2v, y2v, 2); KD_REPLAY(g3, y3, 3);
}

// ---------------------------------------------------------------------------
extern "C" void kernel_launch(void* const* d_in, const int* in_sizes, int n_in,
                              void* d_out, int out_size, void* d_ws, size_t ws_size,
                              hipStream_t stream) {
    const float* wav = (const float*)d_in[0];   // (BS, TLEN)
    const float* Bc  = (const float*)d_in[1];   // (NCH, 5)
    const float* Ac  = (const float*)d_in[2];   // (NCH, 5)
    float* out = (float*)d_out;                 // (BS, NCH, NFRM)

    // workspace (floats): G | y4f (1.03 MB each)
    float* G   = (float*)d_ws;
    float* y4f = G + (size_t)NBK * NCH;

    const float alpha  = (float)exp(-1.0 / 128.0);
    const float beta   = (float)exp(-1.0 / 8.0);
    const float alphaL = (float)exp(-256.0 / 128.0);   // alpha^256 (frame step)

    kF_fused<<<KF_EDGE + KF_MAIN, 128, 0, stream>>>(wav, Bc, Ac, G, y4f, beta, alpha);
    kD_scan_par<<<NSEQ / 4, 256, 0, stream>>>(G, y4f, out, alpha, alphaL);
}